// Round 1
// baseline (144.929 us; speedup 1.0000x reference)
//
#include <hip/hip_runtime.h>

#define SPK 1024
#define UTT 64
#define DIM 256
#define EPSV 1e-5f
#define NROW (SPK * UTT)
#define LOG2E 1.44269504f

typedef __attribute__((ext_vector_type(4))) float f32x4;    // MFMA accumulator
typedef __attribute__((ext_vector_type(2))) long long2v;    // 16 B = 2 fp8 ktile frags

#define EXP2(x) __builtin_amdgcn_exp2f(x)     // bare v_exp_f32, no libm guards

// pack 4 floats -> 4 fp8 e4m3 bytes
__device__ __forceinline__ int pk_fp8(float a, float b, float c, float d) {
    int v = __builtin_amdgcn_cvt_pk_fp8_f32(a, b, 0, false);   // bytes 0,1
    return  __builtin_amdgcn_cvt_pk_fp8_f32(c, d, v, true);    // bytes 2,3
}

// MFMA-fragment byte order for a 256-byte fp8 row/column:
// unit (r,quad) (16 B) = k-bytes [2r*32+quad*8 .. +8] ++ [(2r+1)*32+quad*8 .. +8].
// fragIdx maps original int-group g (bytes g*4..+4) -> stored int index.
__device__ __forceinline__ int fragIdx(int g) {
    return ((g >> 4) * 4 + ((g & 7) >> 1)) * 4 + ((g >> 3) & 1) * 2 + (g & 1);
}

// K1: one block (256 thr) per speaker. Column sums (coalesced 1KB/instr) ->
// csum fp32 [S,D], nrm[s] = ||csum||^2, cincl8 = c_incl quantized x16 into
// e4m3 in MFMA-fragment order (B operand of the fused matmul).
__global__ __launch_bounds__(256)
void k_cent(const float* __restrict__ x, unsigned char* __restrict__ cincl8,
            float* __restrict__ csum, float* __restrict__ nrm) {
    __shared__ float4 sc4[256];
    int s = blockIdx.x, tid = threadIdx.x;
    int dq = tid & 63, ug = tid >> 6;
    const float4* x4 = (const float4*)(x + (size_t)s * UTT * DIM);
    float4 p = {0.f, 0.f, 0.f, 0.f};
#pragma unroll
    for (int i = 0; i < 16; ++i) {
        float4 v = x4[(ug * 16 + i) * 64 + dq];
        p.x += v.x; p.y += v.y; p.z += v.z; p.w += v.w;
    }
    sc4[tid] = p;
    __syncthreads();
    if (tid < 64) {
        float4 a = sc4[dq], b2 = sc4[64 + dq], c = sc4[128 + dq], d = sc4[192 + dq];
        float4 cs = {a.x + b2.x + c.x + d.x, a.y + b2.y + c.y + d.y,
                     a.z + b2.z + c.z + d.z, a.w + b2.w + c.w + d.w};
        ((float4*)csum)[s * 64 + dq] = cs;                     // fp32 csum for K2
        float s2 = cs.x * cs.x + cs.y * cs.y + cs.z * cs.z + cs.w * cs.w;
#pragma unroll
        for (int o = 1; o < 64; o <<= 1) s2 += __shfl_xor(s2, o);
        // c_incl = csum/(||csum|| + U*eps), quantized x16 into e4m3
        float inv = 16.f / (sqrtf(s2) + UTT * EPSV);
        ((int*)cincl8)[s * 64 + fragIdx(dq)] =
            pk_fp8(cs.x * inv, cs.y * inv, cs.z * inv, cs.w * inv);
        if (tid == 0) nrm[s] = s2;
    }
}

// K2: fused normalize+quantize+matmul+softmax-denominator+loss.
// Block = 1 speaker (64 rows), wave = one 16-row mtile. Phase 1: each lane
// loads exactly the 64 x-floats its A-fragment needs (row = lane&15,
// k-chunk = quad), quad-reduces ||x||^2 and x.csum, computes texcl, and
// quantizes A fragments IN REGISTERS (en8 intermediate eliminated).
// Phase 2: double-buffered 64-col slices of cincl8 staged via
// global_load_lds into 1KB regions (lane*16 zero-conflict pattern), 8-deep
// fp8 MFMA chains per ntile, exp2 accumulation with the diag col skipped,
// then per-row logsumexp, block reduce, one atomicAdd.
__global__ __launch_bounds__(256, 2)
void k_fused(const float* __restrict__ x, const unsigned char* __restrict__ cincl8,
             const float* __restrict__ csum, const float* __restrict__ nrm,
             const float* __restrict__ wp, const float* __restrict__ bp,
             float* __restrict__ out) {
    __shared__ unsigned char Bs[2][16 * 1024];   // 2 bufs x 16 regions x 1 KB
    __shared__ float texs[64];
    __shared__ float red[4];
    int tid = threadIdx.x, wave = tid >> 6, lane = tid & 63;
    int quad = lane >> 4, lx = lane & 15;
    int s = blockIdx.x;
    float w = wp[0], b = bp[0];
    float M  = fabsf(w) * 1.0625f + b;           // >= any logit (|sim| <= ~1)
    float wl = w * (LOG2E / 256.f);              // undo x16*x16 quant scale
    float bl = (b - M) * LOG2E;                  // exp(v-M) = exp2(acc*wl + bl)

    // stage 64 cols of B: region (nt=wave, r) = 1 KB; lane ℓ supplies col
    // t*64+wave*16+(ℓ&15), unit (r, ℓ>>4) -> region + ℓ*16 (HW rule).
#define STAGE(buf, t)                                                           \
    _Pragma("unroll")                                                           \
    for (int r = 0; r < 4; ++r) {                                               \
        const unsigned char* g = cincl8 +                                       \
            (size_t)((t) * 64 + wave * 16 + lx) * DIM + (r * 4 + quad) * 16;    \
        __builtin_amdgcn_global_load_lds(                                       \
            (const __attribute__((address_space(1))) void*)g,                   \
            (__attribute__((address_space(3))) void*)(Bs[buf] + (wave * 4 + r) * 1024), \
            16, 0, 0);                                                          \
    }
    STAGE(0, 0);                                 // latency hides under phase 1

    // ---- phase 1 ----
    int arow = wave * 16 + lx;                   // A-operand row this lane owns
    const float* xr = x + ((size_t)s * UTT + arow) * DIM + quad * 8;
    const float* cb = csum + (size_t)s * DIM + quad * 8;
    float4 xv[16];
    float sx = 0.f, sc = 0.f;
#pragma unroll
    for (int kt = 0; kt < 8; ++kt) {             // lane's k-bytes: kt*32+quad*8..+8
        float4 a0 = *(const float4*)(xr + kt * 32);
        float4 a1 = *(const float4*)(xr + kt * 32 + 4);
        float4 c0 = *(const float4*)(cb + kt * 32);
        float4 c1 = *(const float4*)(cb + kt * 32 + 4);
        xv[2 * kt] = a0; xv[2 * kt + 1] = a1;
        sx += a0.x * a0.x + a0.y * a0.y + a0.z * a0.z + a0.w * a0.w
            + a1.x * a1.x + a1.y * a1.y + a1.z * a1.z + a1.w * a1.w;
        sc += a0.x * c0.x + a0.y * c0.y + a0.z * c0.z + a0.w * c0.w
            + a1.x * c1.x + a1.y * c1.y + a1.z * c1.z + a1.w * c1.w;
    }
    // combine the 4 quads (same row, disjoint k-ranges)
    sx += __shfl_xor(sx, 16); sx += __shfl_xor(sx, 32);
    sc += __shfl_xor(sc, 16); sc += __shfl_xor(sc, 32);
    float nx = sqrtf(sx);
    float inv = 16.f / (nx + EPSV);              // x16 into e4m3 (same as before)
    long af[8];                                  // af[kt] = 8 fp8 of ktile kt
#pragma unroll
    for (int kt = 0; kt < 8; ++kt) {
        int lo = pk_fp8(xv[2 * kt].x * inv,     xv[2 * kt].y * inv,
                        xv[2 * kt].z * inv,     xv[2 * kt].w * inv);
        int hi = pk_fp8(xv[2 * kt + 1].x * inv, xv[2 * kt + 1].y * inv,
                        xv[2 * kt + 1].z * inv, xv[2 * kt + 1].w * inv);
        af[kt] = (long)(((unsigned long long)(unsigned)hi << 32) | (unsigned)lo);
    }
    if (quad == 0) {
        // sim_excl = x.(csum-x) / ((||x||+eps)(||csum-x||+63eps))  (fp32 exact)
        float scc = nrm[s];
        float num = sc - sx;
        float e2 = fmaxf(scc - 2.f * sc + sx, 0.f);
        float sim = num / ((nx + EPSV) * (sqrtf(e2) + (UTT - 1) * EPSV));
        texs[arow] = fmaf(sim, w, b);
    }

    float l[4] = {0.f, 0.f, 0.f, 0.f};           // exp-sums for rows quad*4+i
    int s_hi = s >> 6, nt_d = (s >> 4) & 3, lx_d = s & 15;
    __syncthreads();                             // Bs[0] + texs ready

    // ---- phase 2: 16 steps x 64 cols ----
    for (int t = 0; t < 16; ++t) {
        const unsigned char* bsc = Bs[t & 1];
        if (t < 15) { STAGE((t & 1) ^ 1, t + 1); }
#pragma unroll
        for (int nt = 0; nt < 4; ++nt) {         // 4 independent acc chains
            long2v bf2[4];
#pragma unroll
            for (int r = 0; r < 4; ++r)
                bf2[r] = *(const long2v*)(bsc + (nt * 4 + r) * 1024 + lane * 16);
            f32x4 acc = {0.f, 0.f, 0.f, 0.f};
#pragma unroll
            for (int r = 0; r < 4; ++r) {
                acc = __builtin_amdgcn_mfma_f32_16x16x32_fp8_fp8(af[2 * r],     bf2[r].x, acc, 0, 0, 0);
                acc = __builtin_amdgcn_mfma_f32_16x16x32_fp8_fp8(af[2 * r + 1], bf2[r].y, acc, 0, 0, 0);
            }
            bool dg = (t == s_hi) && (nt == nt_d);   // wave-uniform diag tile
#pragma unroll
            for (int i = 0; i < 4; ++i) {
                float e = EXP2(fmaf(acc[i], wl, bl));
                if (!(dg && lx == lx_d)) l[i] += e;  // skip diag col exactly
            }
        }
        __syncthreads();                         // staged buf landed; reads done
    }

    // reduce over the 16 col-lanes; rows live at (quad, i)
#pragma unroll
    for (int o = 1; o < 16; o <<= 1)
#pragma unroll
        for (int i = 0; i < 4; ++i) l[i] += __shfl_xor(l[i], o);

    float cc = 0.f;
    if (lx == 0) {
#pragma unroll
        for (int i = 0; i < 4; ++i) {
            float tex = texs[wave * 16 + quad * 4 + i];
            cc += (M + __logf(l[i] + EXP2((tex - M) * LOG2E))) - tex;  // lse - target
        }
    }
#pragma unroll
    for (int o = 1; o < 64; o <<= 1) cc += __shfl_xor(cc, o);
    if (lane == 0) red[wave] = cc;
    __syncthreads();
    if (tid == 0)
        atomicAdd(out, (red[0] + red[1] + red[2] + red[3]) * (1.f / NROW));
}

extern "C" void kernel_launch(void* const* d_in, const int* in_sizes, int n_in,
                              void* d_out, int out_size, void* d_ws, size_t ws_size,
                              hipStream_t stream) {
    const float* x  = (const float*)d_in[0];
    const float* wp = (const float*)d_in[1];
    const float* bp = (const float*)d_in[2];
    char* ws = (char*)d_ws;
    unsigned char* cincl8 = (unsigned char*)ws;                 // @0,    256 KB
    float* csum           = (float*)(ws + (1u << 19));          // @512K, 1 MB
    float* nrm            = (float*)(ws + (2u << 20));          // @2M,   4 KB
    float* out = (float*)d_out;

    hipMemsetAsync(d_out, 0, sizeof(float), stream);
    k_cent <<<SPK, 256, 0, stream>>>(x, cincl8, csum, nrm);
    k_fused<<<SPK, 256, 0, stream>>>(x, cincl8, csum, nrm, wp, bp, out);
}

// Round 2
// 141.959 us; speedup vs baseline: 1.0209x; 1.0209x over previous
//
#include <hip/hip_runtime.h>

#define SPK 1024
#define UTT 64
#define DIM 256
#define EPSV 1e-5f
#define NROW (SPK * UTT)
#define LOG2E 1.44269504f
#define ASTRIDE 34      // longs per row in the A-share (272 B: 16B-aligned, ~4-way banks)

typedef __attribute__((ext_vector_type(4))) float f32x4;    // MFMA accumulator
typedef __attribute__((ext_vector_type(2))) long long2v;    // 16 B = 2 fp8 ktile frags

#define EXP2(x) __builtin_amdgcn_exp2f(x)     // bare v_exp_f32, no libm guards

// pack 4 floats -> 4 fp8 e4m3 bytes
__device__ __forceinline__ int pk_fp8(float a, float b, float c, float d) {
    int v = __builtin_amdgcn_cvt_pk_fp8_f32(a, b, 0, false);   // bytes 0,1
    return  __builtin_amdgcn_cvt_pk_fp8_f32(c, d, v, true);    // bytes 2,3
}

// MFMA-fragment byte order for a 256-byte fp8 row/column:
// unit (r,quad) (16 B) = k-bytes [2r*32+quad*8 .. +8] ++ [(2r+1)*32+quad*8 .. +8].
// fragIdx maps original int-group g (bytes g*4..+4) -> stored int index.
__device__ __forceinline__ int fragIdx(int g) {
    return ((g >> 4) * 4 + ((g & 7) >> 1)) * 4 + ((g >> 3) & 1) * 2 + (g & 1);
}

// K1: one block (256 thr) per speaker. Column sums (coalesced 1KB/instr) ->
// csum fp32 [S,D], nrm[s] = ||csum||^2, cincl8 = c_incl quantized x16 into
// e4m3 in MFMA-fragment order (B operand of the fused matmul).
__global__ __launch_bounds__(256)
void k_cent(const float* __restrict__ x, unsigned char* __restrict__ cincl8,
            float* __restrict__ csum, float* __restrict__ nrm) {
    __shared__ float4 sc4[256];
    int s = blockIdx.x, tid = threadIdx.x;
    int dq = tid & 63, ug = tid >> 6;
    const float4* x4 = (const float4*)(x + (size_t)s * UTT * DIM);
    float4 p = {0.f, 0.f, 0.f, 0.f};
#pragma unroll
    for (int i = 0; i < 16; ++i) {
        float4 v = x4[(ug * 16 + i) * 64 + dq];
        p.x += v.x; p.y += v.y; p.z += v.z; p.w += v.w;
    }
    sc4[tid] = p;
    __syncthreads();
    if (tid < 64) {
        float4 a = sc4[dq], b2 = sc4[64 + dq], c = sc4[128 + dq], d = sc4[192 + dq];
        float4 cs = {a.x + b2.x + c.x + d.x, a.y + b2.y + c.y + d.y,
                     a.z + b2.z + c.z + d.z, a.w + b2.w + c.w + d.w};
        ((float4*)csum)[s * 64 + dq] = cs;                     // fp32 csum for K2
        float s2 = cs.x * cs.x + cs.y * cs.y + cs.z * cs.z + cs.w * cs.w;
#pragma unroll
        for (int o = 1; o < 64; o <<= 1) s2 += __shfl_xor(s2, o);
        // c_incl = csum/(||csum|| + U*eps), quantized x16 into e4m3
        float inv = 16.f / (sqrtf(s2) + UTT * EPSV);
        ((int*)cincl8)[s * 64 + fragIdx(dq)] =
            pk_fp8(cs.x * inv, cs.y * inv, cs.z * inv, cs.w * inv);
        if (tid == 0) nrm[s] = s2;
    }
}

// K2: fused normalize+quantize+matmul+softmax-denominator+loss.
// Block = 1 speaker. Phase 1: wave w loads rows w*16+lx (lane owns the
// (row, quad) A-slice), quad-reduces ||x||^2 / x.csum, computes texcl,
// quantizes its fragments and shares them via LDS so every wave gets all
// 4 m-tiles (64 rows) in registers (64 VGPR). Phase 2: wave w owns a fixed
// 16-col n-tile per 64-col step; its B-fragments (4 x 16 B per lane) are
// loaded DIRECTLY from L2 (cincl8 is a 256 KB hot set), prefetched one
// step ahead. No LDS, no barriers, no vmcnt drains in the main loop;
// B reuse (1 load : 8 MFMAs) comes from A-in-registers.
__global__ __launch_bounds__(256, 4)
void k_fused(const float* __restrict__ x, const unsigned char* __restrict__ cincl8,
             const float* __restrict__ csum, const float* __restrict__ nrm,
             const float* __restrict__ wp, const float* __restrict__ bp,
             float* __restrict__ out) {
    __shared__ long shareA[64 * ASTRIDE];        // 17 KB A-fragment exchange
    __shared__ float texs[64];
    __shared__ float fin[4][64];
    int tid = threadIdx.x, wave = tid >> 6, lane = tid & 63;
    int quad = lane >> 4, lx = lane & 15;
    int s = blockIdx.x;
    float w = wp[0], b = bp[0];
    float M  = fabsf(w) * 1.0625f + b;           // >= any logit (|sim| <= ~1)
    float wl = w * (LOG2E / 256.f);              // undo x16*x16 quant scale
    float bl = (b - M) * LOG2E;                  // exp(v-M) = exp2(acc*wl + bl)

    // ---- phase 1 ----
    int arow = wave * 16 + lx;                   // A-operand row this lane owns
    const float* xr = x + ((size_t)s * UTT + arow) * DIM + quad * 8;
    const float* cb = csum + (size_t)s * DIM + quad * 8;
    float4 xv[16];
    float sx = 0.f, sc = 0.f;
#pragma unroll
    for (int kt = 0; kt < 8; ++kt) {             // lane's k-bytes: kt*32+quad*8..+8
        float4 a0 = *(const float4*)(xr + kt * 32);
        float4 a1 = *(const float4*)(xr + kt * 32 + 4);
        float4 c0 = *(const float4*)(cb + kt * 32);
        float4 c1 = *(const float4*)(cb + kt * 32 + 4);
        xv[2 * kt] = a0; xv[2 * kt + 1] = a1;
        sx += a0.x * a0.x + a0.y * a0.y + a0.z * a0.z + a0.w * a0.w
            + a1.x * a1.x + a1.y * a1.y + a1.z * a1.z + a1.w * a1.w;
        sc += a0.x * c0.x + a0.y * c0.y + a0.z * c0.z + a0.w * c0.w
            + a1.x * c1.x + a1.y * c1.y + a1.z * c1.z + a1.w * c1.w;
    }
    // combine the 4 quads (same row, disjoint k-ranges)
    sx += __shfl_xor(sx, 16); sx += __shfl_xor(sx, 32);
    sc += __shfl_xor(sc, 16); sc += __shfl_xor(sc, 32);
    float nx = sqrtf(sx);
    float inv = 16.f / (nx + EPSV);              // x16 into e4m3
    long* shp = &shareA[arow * ASTRIDE + quad * 8];
#pragma unroll
    for (int r = 0; r < 4; ++r) {                // ktiles 2r, 2r+1 as one b128
        int a_lo = pk_fp8(xv[4 * r + 0].x * inv, xv[4 * r + 0].y * inv,
                          xv[4 * r + 0].z * inv, xv[4 * r + 0].w * inv);
        int a_hi = pk_fp8(xv[4 * r + 1].x * inv, xv[4 * r + 1].y * inv,
                          xv[4 * r + 1].z * inv, xv[4 * r + 1].w * inv);
        int b_lo = pk_fp8(xv[4 * r + 2].x * inv, xv[4 * r + 2].y * inv,
                          xv[4 * r + 2].z * inv, xv[4 * r + 2].w * inv);
        int b_hi = pk_fp8(xv[4 * r + 3].x * inv, xv[4 * r + 3].y * inv,
                          xv[4 * r + 3].z * inv, xv[4 * r + 3].w * inv);
        long2v pr;
        pr.x = (long)(((unsigned long long)(unsigned)a_hi << 32) | (unsigned)a_lo);
        pr.y = (long)(((unsigned long long)(unsigned)b_hi << 32) | (unsigned)b_lo);
        *(long2v*)(shp + 2 * r) = pr;
    }
    if (quad == 0) {
        // sim_excl = x.(csum-x) / ((||x||+eps)(||csum-x||+63eps))  (fp32 exact)
        float scc = nrm[s];
        float num = sc - sx;
        float e2 = fmaxf(scc - 2.f * sc + sx, 0.f);
        float sim = num / ((nx + EPSV) * (sqrtf(e2) + (UTT - 1) * EPSV));
        texs[arow] = fmaf(sim, w, b);
    }
    __syncthreads();                             // shareA + texs ready

    // every wave pulls all 4 m-tiles' A-fragments into registers (one-time)
    long2v af[4][4];
#pragma unroll
    for (int mt = 0; mt < 4; ++mt)
#pragma unroll
        for (int r = 0; r < 4; ++r)
            af[mt][r] = *(const long2v*)(&shareA[(mt * 16 + lx) * ASTRIDE + quad * 8 + 2 * r]);

    // ---- phase 2: 16 steps x 16 cols/wave, B direct from L2, 1-deep prefetch ----
    float l[16];
#pragma unroll
    for (int i = 0; i < 16; ++i) l[i] = 0.f;
    int t_d = s >> 6, w_d = (s >> 4) & 3, lx_d = s & 15;
    const unsigned char* bp_ = cincl8 + (size_t)(wave * 16 + lx) * DIM + quad * 16;

    long2v bfc[4], bfn[4];
#pragma unroll
    for (int r = 0; r < 4; ++r) bfc[r] = *(const long2v*)(bp_ + r * 64);

    for (int t = 0; t < 16; ++t) {
        const unsigned char* bn = bp_ + (size_t)(((t + 1) & 15) * 64) * DIM;
#pragma unroll
        for (int r = 0; r < 4; ++r)              // prefetch next step's B
            bfn[r] = *(const long2v*)(bn + r * 64);
        f32x4 acc[4] = {{0.f,0.f,0.f,0.f},{0.f,0.f,0.f,0.f},
                        {0.f,0.f,0.f,0.f},{0.f,0.f,0.f,0.f}};
#pragma unroll
        for (int r = 0; r < 4; ++r) {            // 4 independent 8-deep chains
#pragma unroll
            for (int mt = 0; mt < 4; ++mt)
                acc[mt] = __builtin_amdgcn_mfma_f32_16x16x32_fp8_fp8(af[mt][r].x, bfc[r].x, acc[mt], 0, 0, 0);
#pragma unroll
            for (int mt = 0; mt < 4; ++mt)
                acc[mt] = __builtin_amdgcn_mfma_f32_16x16x32_fp8_fp8(af[mt][r].y, bfc[r].y, acc[mt], 0, 0, 0);
        }
#pragma unroll
        for (int mt = 0; mt < 4; ++mt)
#pragma unroll
            for (int i = 0; i < 4; ++i)
                l[mt * 4 + i] += EXP2(fmaf(acc[mt][i], wl, bl));
        if (t == t_d && wave == w_d) {           // wave-uniform: undo diag col
#pragma unroll
            for (int mt = 0; mt < 4; ++mt)
#pragma unroll
                for (int i = 0; i < 4; ++i) {
                    float e = EXP2(fmaf(acc[mt][i], wl, bl));
                    if (lx == lx_d) l[mt * 4 + i] -= e;
                }
        }
#pragma unroll
        for (int r = 0; r < 4; ++r) bfc[r] = bfn[r];
    }

    // reduce over the 16 col-lanes; rows live at (mt, quad, i)
#pragma unroll
    for (int o = 1; o < 16; o <<= 1)
#pragma unroll
        for (int i = 0; i < 16; ++i) l[i] += __shfl_xor(l[i], o);
    if (lx == 0)
#pragma unroll
        for (int mt = 0; mt < 4; ++mt)
#pragma unroll
            for (int i = 0; i < 4; ++i)
                fin[wave][mt * 16 + quad * 4 + i] = l[mt * 4 + i];
    __syncthreads();

    if (tid < 64) {                              // row = tid: combine 4 wave-partials
        float D = fin[0][tid] + fin[1][tid] + fin[2][tid] + fin[3][tid];
        float tex = texs[tid];
        float cc = (M + __logf(D + EXP2((tex - M) * LOG2E))) - tex;  // lse - target
#pragma unroll
        for (int o = 1; o < 64; o <<= 1) cc += __shfl_xor(cc, o);
        if (tid == 0) atomicAdd(out, cc * (1.f / NROW));
    }
}

extern "C" void kernel_launch(void* const* d_in, const int* in_sizes, int n_in,
                              void* d_out, int out_size, void* d_ws, size_t ws_size,
                              hipStream_t stream) {
    const float* x  = (const float*)d_in[0];
    const float* wp = (const float*)d_in[1];
    const float* bp = (const float*)d_in[2];
    char* ws = (char*)d_ws;
    unsigned char* cincl8 = (unsigned char*)ws;                 // @0,    256 KB
    float* csum           = (float*)(ws + (1u << 19));          // @512K, 1 MB
    float* nrm            = (float*)(ws + (2u << 20));          // @2M,   4 KB
    float* out = (float*)d_out;

    hipMemsetAsync(d_out, 0, sizeof(float), stream);
    k_cent <<<SPK, 256, 0, stream>>>(x, cincl8, csum, nrm);
    k_fused<<<SPK, 256, 0, stream>>>(x, cincl8, csum, nrm, wp, bp, out);
}